// Round 12
// baseline (50.743 us; speedup 1.0000x reference)
//
#include <hip/hip_runtime.h>
#include <hip/hip_bf16.h>

#define F_IN 128
#define F_OUT 64

typedef __attribute__((ext_vector_type(8))) short short8;
typedef __attribute__((ext_vector_type(4))) float f32x4;

__device__ __forceinline__ unsigned short f2bf_rne(float f) {
  unsigned int u = __builtin_bit_cast(unsigned int, f);
  u += 0x7fffu + ((u >> 16) & 1u);
  return (unsigned short)(u >> 16);
}
__device__ __forceinline__ float bf_lo(unsigned int u) {
  return __builtin_bit_cast(float, u << 16);
}
__device__ __forceinline__ float bf_hi(unsigned int u) {
  return __builtin_bit_cast(float, u & 0xffff0000u);
}

// ---------------------------------------------------------------------------
// Kernel A (fused): blocks [0, gemm_blocks) compute pre = bf16(x @ W) via
// MFMA; blocks [gemm_blocks, ..) compute row_ptr by binary search.
// (R6-exact GEMM: scattered u16 staging, 1 MFMA per (ks,nt), absmax 1.0.)
// ---------------------------------------------------------------------------
__global__ __launch_bounds__(256) void gcn_gemm_rowptr(
    const float* __restrict__ x, const float* __restrict__ w,
    unsigned short* __restrict__ pre,
    const int* __restrict__ edge_row, int* __restrict__ row_ptr,
    int n_nodes, int n_edges, int gemm_blocks) {
  const int tid = threadIdx.x;

  if (blockIdx.x >= gemm_blocks) {  // ---- rowptr path ----
    const int r = (blockIdx.x - gemm_blocks) * 256 + tid;
    if (r > n_nodes) return;
    int lo = 0, hi = n_edges;
    while (lo < hi) {
      const int mid = (lo + hi) >> 1;
      if (edge_row[mid] < r) lo = mid + 1; else hi = mid;
    }
    row_ptr[r] = lo;
    return;
  }

  // ---- GEMM path ----
  __shared__ __align__(16) unsigned short wt_hi[64 * 128];  // 16 KB

  {  // stage W^T: coalesced float4 reads, convert, scatter u16 into LDS
#pragma unroll
    for (int i = 0; i < 8; ++i) {
      const int flat4 = tid + i * 256;
      const float4 v = ((const float4*)w)[flat4];
      const float fv[4] = {v.x, v.y, v.z, v.w};
#pragma unroll
      for (int j = 0; j < 4; ++j) {
        const int flat = flat4 * 4 + j;          // flat = k*64 + n
        const int k = flat >> 6;
        const int n = flat & 63;
        int off = (n << 8) + (k << 1);
        off ^= (n & 7) << 4;
        *(unsigned short*)((char*)wt_hi + off) = f2bf_rne(fv[j]);
      }
    }
  }
  __syncthreads();

  const int lane = tid & 63;
  const int mt = blockIdx.x * 4 + (tid >> 6);
  const int m0 = mt * 16;
  if (m0 >= n_nodes) return;

  const int lrow = lane & 15;
  const int lk = lane >> 4;
  const bool full = (m0 + 16 <= n_nodes);
  const int arow = full ? (m0 + lrow) : min(m0 + lrow, n_nodes - 1);

  f32x4 acc[4];
#pragma unroll
  for (int i = 0; i < 4; ++i) acc[i] = (f32x4){0.f, 0.f, 0.f, 0.f};

#pragma unroll
  for (int ks = 0; ks < 4; ++ks) {
    const float4* xp =
        (const float4*)(x + (size_t)arow * F_IN + ks * 32 + lk * 8);
    const float4 q0 = xp[0];
    const float4 q1 = xp[1];
    const float fv[8] = {q0.x, q0.y, q0.z, q0.w, q1.x, q1.y, q1.z, q1.w};
    short8 ah;
#pragma unroll
    for (int i = 0; i < 8; ++i) ah[i] = (short)f2bf_rne(fv[i]);
#pragma unroll
    for (int nt = 0; nt < 4; ++nt) {
      const int n = nt * 16 + lrow;
      int off = (n << 8) + (ks * 64 + lk * 16);
      off ^= (n & 7) << 4;
      const short8 bh = *(const short8*)((const char*)wt_hi + off);
      acc[nt] = __builtin_amdgcn_mfma_f32_16x16x32_bf16(ah, bh, acc[nt], 0, 0, 0);
    }
  }

  // C/D: col = lane&15, row = (lane>>4)*4 + reg  [HW-verified]
#pragma unroll
  for (int nt = 0; nt < 4; ++nt) {
#pragma unroll
    for (int r = 0; r < 4; ++r) {
      const int row = m0 + lk * 4 + r;
      if (full || row < n_nodes)
        pre[(size_t)row * F_OUT + nt * 16 + lrow] = f2bf_rne(acc[nt][r]);
    }
  }
}

// ---------------------------------------------------------------------------
// Kernel B: out[r][f] = relu( sum_e val[e] * pre_bf16[col[e]][f] )
// (R6-exact, best measured.) One wave per row, half-wave per edge; per
// 16-edge group: 16 shuffle-pairs, then 8 independent gathers issued
// back-to-back, then 16 fmas on 4 accumulators. Idempotent: launched twice
// this round as a TIMING PROBE (dur - baseline = spmm + gap).
// ---------------------------------------------------------------------------
__global__ __launch_bounds__(256) void gcn_spmm(
    const unsigned short* __restrict__ pre, const int* __restrict__ row_ptr,
    const int* __restrict__ edge_col, const float* __restrict__ edge_val,
    float* __restrict__ out, int n_nodes) {
  const int lane = threadIdx.x & 63;
  const int half = lane >> 5;
  const int fl = lane & 31;
  int row = (int)((blockIdx.x * blockDim.x + threadIdx.x) >> 6);
  row = __builtin_amdgcn_readfirstlane(row);
  if (row >= n_nodes) return;
  const int e0 = row_ptr[row];
  const int e1 = row_ptr[row + 1];

  float a0 = 0.f, a1 = 0.f, a2 = 0.f, a3 = 0.f;
  const char* prebase = (const char*)pre + ((size_t)fl << 2);  // fl-th uint

  for (int base = e0; base < e1; base += 64) {
    const int cnt = min(64, e1 - base);
    int myc = 0;
    float myv = 0.f;
    if (lane < cnt) {
      myc = edge_col[base + lane] << 7;  // byte offset of the row (64*2B)
      myv = edge_val[base + lane];
    }
    const int nb = (cnt + 15) >> 4;  // 16 edges per iteration
    for (int b = 0; b < nb; ++b) {
      const int j0 = b * 16;
      int   cc[8];
      float vv[8];
#pragma unroll
      for (int j = 0; j < 8; ++j) {
        const int idx = j0 + j * 2 + half;
        cc[j] = __shfl(myc, idx);
        vv[j] = __shfl(myv, idx);
      }
      unsigned int p[8];
#pragma unroll
      for (int j = 0; j < 8; ++j)
        p[j] = *(const unsigned int*)(prebase + (size_t)(unsigned int)cc[j]);
#pragma unroll
      for (int j = 0; j < 8; j += 2) {
        a0 = fmaf(vv[j], bf_lo(p[j]), a0);
        a1 = fmaf(vv[j], bf_hi(p[j]), a1);
        a2 = fmaf(vv[j + 1], bf_lo(p[j + 1]), a2);
        a3 = fmaf(vv[j + 1], bf_hi(p[j + 1]), a3);
      }
    }
  }

  // merge edge-parity halves: lanes l and l^32 hold the same feature pair
  float s0 = (a0 + a2) + __shfl_xor(a0 + a2, 32);
  float s1 = (a1 + a3) + __shfl_xor(a1 + a3, 32);
  if (half == 0) {
    float2 o = make_float2(fmaxf(s0, 0.f), fmaxf(s1, 0.f));
    *(float2*)(out + (size_t)row * F_OUT + fl * 2) = o;
  }
}

extern "C" void kernel_launch(void* const* d_in, const int* in_sizes, int n_in,
                              void* d_out, int out_size, void* d_ws, size_t ws_size,
                              hipStream_t stream) {
  const float* x        = (const float*)d_in[0];
  const float* w        = (const float*)d_in[1];
  const int*   edge_row = (const int*)d_in[2];
  const int*   edge_col = (const int*)d_in[3];
  const float* edge_val = (const float*)d_in[4];
  float* out = (float*)d_out;

  const int n_nodes = in_sizes[0] / F_IN;   // 50000
  const int n_edges = in_sizes[2];          // 800000

  unsigned short* pre = (unsigned short*)d_ws;  // n_nodes*64 bf16 = 6.4 MB
  int* row_ptr = (int*)((char*)d_ws +
                        (size_t)n_nodes * F_OUT * sizeof(unsigned short));

  const int m_tiles = (n_nodes + 15) / 16;
  const int gemm_blocks = (m_tiles + 3) / 4;
  const int rp_blocks = (n_nodes + 1 + 255) / 256;
  gcn_gemm_rowptr<<<gemm_blocks + rp_blocks, 256, 0, stream>>>(
      x, w, pre, edge_row, row_ptr, n_nodes, n_edges, gemm_blocks);

  const int spmm_blocks = ((size_t)n_nodes * 64 + 255) / 256;
  // TIMING PROBE: spmm launched twice (idempotent overwrite of d_out).
  // dur_us(this round) - dur_us(R6 baseline) = spmm time + launch gap.
  gcn_spmm<<<spmm_blocks, 256, 0, stream>>>(pre, row_ptr, edge_col, edge_val,
                                            out, n_nodes);
  gcn_spmm<<<spmm_blocks, 256, 0, stream>>>(pre, row_ptr, edge_col, edge_val,
                                            out, n_nodes);
}

// Round 13
// 33.554 us; speedup vs baseline: 1.5123x; 1.5123x over previous
//
#include <hip/hip_runtime.h>
#include <hip/hip_bf16.h>

#define F_IN 128
#define F_OUT 64

typedef __attribute__((ext_vector_type(8))) short short8;
typedef __attribute__((ext_vector_type(4))) float f32x4;

__device__ __forceinline__ unsigned short f2bf_rne(float f) {
  unsigned int u = __builtin_bit_cast(unsigned int, f);
  u += 0x7fffu + ((u >> 16) & 1u);
  return (unsigned short)(u >> 16);
}
__device__ __forceinline__ float bf_lo(unsigned int u) {
  return __builtin_bit_cast(float, u << 16);
}
__device__ __forceinline__ float bf_hi(unsigned int u) {
  return __builtin_bit_cast(float, u & 0xffff0000u);
}

// ---------------------------------------------------------------------------
// Kernel A (fused): blocks [0, gemm_blocks): pre = bf16(x @ W) via MFMA,
// 64-ROW TILE per block, x staged through LDS; blocks [gemm_blocks, ..):
// row_ptr binary search.
//
// Layout (both wt and xs): row-major 256 B/row of bf16, 16 B chunk c of row
// r stored at  r*256 + ((c ^ (r&7))<<4).  Bank arithmetic: fragment reads
// (lanes = 16 rows x 4 k-chunks) spread exactly 8 lanes per 4-bank group =
// the b128 data-volume minimum -> conflict-free.
//
// x staging: thread reads float4 at flat4 = tid + i*256 (PERFECTLY dense
// coalesced, 8 loads back-to-back = high MLP), converts to bf16x4, one
// ds_write_b64 to the swizzled slot. Replaces per-lane scattered 32 B
// global reads (16 txns/instr) + in-loop cvt with clean streaming.
// ---------------------------------------------------------------------------
__global__ __launch_bounds__(256) void gcn_gemm_rowptr(
    const float* __restrict__ x, const float* __restrict__ w,
    unsigned short* __restrict__ pre,
    const int* __restrict__ edge_row, int* __restrict__ row_ptr,
    int n_nodes, int n_edges, int gemm_blocks) {
  const int tid = threadIdx.x;

  if (blockIdx.x >= gemm_blocks) {  // ---- rowptr path ----
    const int r = (blockIdx.x - gemm_blocks) * 256 + tid;
    if (r > n_nodes) return;
    int lo = 0, hi = n_edges;
    while (lo < hi) {
      const int mid = (lo + hi) >> 1;
      if (edge_row[mid] < r) lo = mid + 1; else hi = mid;
    }
    row_ptr[r] = lo;
    return;
  }

  // ---- GEMM path ----
  __shared__ __align__(16) unsigned short wt[64 * 128];  // 16 KB W^T bf16
  __shared__ __align__(16) unsigned short xs[64 * 128];  // 16 KB x-tile bf16

  {  // stage W^T: wave-uniform k-rows, lane-contiguous n reads; b128 writes
    const int n  = tid & 63;
    const int kc = (tid >> 6) * 32;  // wave-uniform
#pragma unroll
    for (int j = 0; j < 4; ++j) {
      short8 hv;
#pragma unroll
      for (int i = 0; i < 8; ++i)
        hv[i] = (short)f2bf_rne(w[(kc + j * 8 + i) * F_OUT + n]);
      int off = (n << 8) + ((kc + j * 8) << 1);
      off ^= (n & 7) << 4;
      *(short8*)((char*)wt + off) = hv;
    }
  }

  const int m0blk = blockIdx.x * 64;
  {  // stage x tile: dense coalesced float4 reads -> bf16 -> swizzled b64
    const int maxf4 = (min(64, n_nodes - m0blk)) * 32;  // valid float4 count
    const float4* x4 = (const float4*)(x + (size_t)m0blk * F_IN);
#pragma unroll
    for (int i = 0; i < 8; ++i) {
      const int f4 = tid + i * 256;
      const float4 v = x4[min(f4, maxf4 - 1)];
      const int fc = min(f4, maxf4 - 1);
      const int r = fc >> 5;        // row in tile
      const int c4 = fc & 31;       // float4 index in row
      const int c = c4 >> 1;        // 16B chunk
      const int h = c4 & 1;         // half within chunk
      unsigned short b[4] = {f2bf_rne(v.x), f2bf_rne(v.y),
                             f2bf_rne(v.z), f2bf_rne(v.w)};
      const int off = (r << 8) + (((c ^ (r & 7)) << 4) + (h << 3));
      *(unsigned long long*)((char*)xs + off) =
          __builtin_bit_cast(unsigned long long,
                             *(const ulong1*)&b[0]);
    }
  }
  __syncthreads();

  const int lane = tid & 63;
  const int lrow = lane & 15;
  const int lk = lane >> 4;
  const int rloc = (tid >> 6) * 16 + lrow;  // local row in 64-row tile
  const int grow = m0blk + (tid >> 6) * 16; // wave's first global row
  if (grow >= n_nodes) return;
  const bool full = (grow + 16 <= n_nodes);

  f32x4 acc[4];
#pragma unroll
  for (int i = 0; i < 4; ++i) acc[i] = (f32x4){0.f, 0.f, 0.f, 0.f};

#pragma unroll
  for (int ks = 0; ks < 4; ++ks) {
    int aoff = (rloc << 8) + (((ks * 4 + lk) ^ (rloc & 7)) << 4);
    const short8 av = *(const short8*)((const char*)xs + aoff);
#pragma unroll
    for (int nt = 0; nt < 4; ++nt) {
      const int n = nt * 16 + lrow;
      int boff = (n << 8) + (((ks * 4 + lk) ^ (n & 7)) << 4);
      const short8 bh = *(const short8*)((const char*)wt + boff);
      acc[nt] = __builtin_amdgcn_mfma_f32_16x16x32_bf16(av, bh, acc[nt], 0, 0, 0);
    }
  }

  // C/D: col = lane&15, row = (lane>>4)*4 + reg  [HW-verified]
#pragma unroll
  for (int nt = 0; nt < 4; ++nt) {
#pragma unroll
    for (int r = 0; r < 4; ++r) {
      const int row = grow + lk * 4 + r;
      if (full || row < n_nodes)
        pre[(size_t)row * F_OUT + nt * 16 + lrow] = f2bf_rne(acc[nt][r]);
    }
  }
}

// ---------------------------------------------------------------------------
// Kernel B: out[r][f] = relu( sum_e val[e] * pre_bf16[col[e]][f] )
// (R6-exact, best measured.) One wave per row, half-wave per edge; per
// 16-edge group: 16 shuffle-pairs, then 8 independent gathers issued
// back-to-back, then 16 fmas on 4 accumulators. Fixed order -> deterministic.
// ---------------------------------------------------------------------------
__global__ __launch_bounds__(256) void gcn_spmm(
    const unsigned short* __restrict__ pre, const int* __restrict__ row_ptr,
    const int* __restrict__ edge_col, const float* __restrict__ edge_val,
    float* __restrict__ out, int n_nodes) {
  const int lane = threadIdx.x & 63;
  const int half = lane >> 5;
  const int fl = lane & 31;
  int row = (int)((blockIdx.x * blockDim.x + threadIdx.x) >> 6);
  row = __builtin_amdgcn_readfirstlane(row);
  if (row >= n_nodes) return;
  const int e0 = row_ptr[row];
  const int e1 = row_ptr[row + 1];

  float a0 = 0.f, a1 = 0.f, a2 = 0.f, a3 = 0.f;
  const char* prebase = (const char*)pre + ((size_t)fl << 2);  // fl-th uint

  for (int base = e0; base < e1; base += 64) {
    const int cnt = min(64, e1 - base);
    int myc = 0;
    float myv = 0.f;
    if (lane < cnt) {
      myc = edge_col[base + lane] << 7;  // byte offset of the row (64*2B)
      myv = edge_val[base + lane];
    }
    const int nb = (cnt + 15) >> 4;  // 16 edges per iteration
    for (int b = 0; b < nb; ++b) {
      const int j0 = b * 16;
      int   cc[8];
      float vv[8];
#pragma unroll
      for (int j = 0; j < 8; ++j) {
        const int idx = j0 + j * 2 + half;
        cc[j] = __shfl(myc, idx);
        vv[j] = __shfl(myv, idx);
      }
      unsigned int p[8];
#pragma unroll
      for (int j = 0; j < 8; ++j)
        p[j] = *(const unsigned int*)(prebase + (size_t)(unsigned int)cc[j]);
#pragma unroll
      for (int j = 0; j < 8; j += 2) {
        a0 = fmaf(vv[j], bf_lo(p[j]), a0);
        a1 = fmaf(vv[j], bf_hi(p[j]), a1);
        a2 = fmaf(vv[j + 1], bf_lo(p[j + 1]), a2);
        a3 = fmaf(vv[j + 1], bf_hi(p[j + 1]), a3);
      }
    }
  }

  // merge edge-parity halves: lanes l and l^32 hold the same feature pair
  float s0 = (a0 + a2) + __shfl_xor(a0 + a2, 32);
  float s1 = (a1 + a3) + __shfl_xor(a1 + a3, 32);
  if (half == 0) {
    float2 o = make_float2(fmaxf(s0, 0.f), fmaxf(s1, 0.f));
    *(float2*)(out + (size_t)row * F_OUT + fl * 2) = o;
  }
}

extern "C" void kernel_launch(void* const* d_in, const int* in_sizes, int n_in,
                              void* d_out, int out_size, void* d_ws, size_t ws_size,
                              hipStream_t stream) {
  const float* x        = (const float*)d_in[0];
  const float* w        = (const float*)d_in[1];
  const int*   edge_row = (const int*)d_in[2];
  const int*   edge_col = (const int*)d_in[3];
  const float* edge_val = (const float*)d_in[4];
  float* out = (float*)d_out;

  const int n_nodes = in_sizes[0] / F_IN;   // 50000
  const int n_edges = in_sizes[2];          // 800000

  unsigned short* pre = (unsigned short*)d_ws;  // n_nodes*64 bf16 = 6.4 MB
  int* row_ptr = (int*)((char*)d_ws +
                        (size_t)n_nodes * F_OUT * sizeof(unsigned short));

  const int gemm_blocks = (n_nodes + 63) / 64;   // 64-row tiles
  const int rp_blocks = (n_nodes + 1 + 255) / 256;
  gcn_gemm_rowptr<<<gemm_blocks + rp_blocks, 256, 0, stream>>>(
      x, w, pre, edge_row, row_ptr, n_nodes, n_edges, gemm_blocks);

  const int spmm_blocks = ((size_t)n_nodes * 64 + 255) / 256;
  gcn_spmm<<<spmm_blocks, 256, 0, stream>>>(pre, row_ptr, edge_col, edge_val,
                                            out, n_nodes);
}